// Round 1
// baseline (96.531 us; speedup 1.0000x reference)
//
#include <hip/hip_runtime.h>
#include <math.h>

#define HW_PIX 65536   // 256*256
#define HID_N 64
#define TDIM 512
#define NBATCH 16

__device__ __forceinline__ float wred64(float v) {
#pragma unroll
    for (int off = 32; off > 0; off >>= 1) v += __shfl_xor(v, off, 64);
    return v;
}

// ws layout (floats):
//  [b*8 + 0..4]  : u0,u1,u2, s, tnorm   (per batch b = 0..15)
//  [128 + 0..5]  : G00,G01,G02,G11,G12,G22
//  [128 + 6..14] : M row-major (3x3)
//  [128 +15..17] : v
//  [128 +18..20] : g
//  [128 +21]     : bnorm
__global__ __launch_bounds__(256) void prep_kernel(
    const float* __restrict__ text_vec,    // (16,512)
    const float* __restrict__ text_proj_w, // (64,512)
    const float* __restrict__ text_proj_b, // (64)
    const float* __restrict__ z_proj_w,    // (64,3)
    const float* __restrict__ z_proj_b,    // (64)
    const float* __restrict__ out_w,       // (3,64)
    float* __restrict__ ws)
{
    const int b   = blockIdx.x;
    const int tid = threadIdx.x;
    const int o   = tid >> 2;   // output channel 0..63
    const int q   = tid & 3;    // quarter of the 512-dot

    const float4* tv   = (const float4*)(text_vec + (size_t)b * TDIM);
    const float4* wrow = (const float4*)(text_proj_w + (size_t)o * TDIM);

    float acc = 0.f;
#pragma unroll 8
    for (int i = q * 32; i < q * 32 + 32; ++i) {
        float4 a = tv[i];
        float4 w = wrow[i];
        acc = fmaf(a.x, w.x, fmaf(a.y, w.y, fmaf(a.z, w.z, fmaf(a.w, w.w, acc))));
    }
    // combine the 4 quarters (consecutive lanes within a wave)
    acc += __shfl_xor(acc, 1, 64);
    acc += __shfl_xor(acc, 2, 64);

    __shared__ float t_sh[HID_N];
    if (q == 0) t_sh[o] = acc + text_proj_b[o];
    __syncthreads();

    if (tid < 64) {   // wave 0 does all reductions
        float t  = t_sh[tid];
        float w0 = z_proj_w[tid * 3 + 0];
        float w1 = z_proj_w[tid * 3 + 1];
        float w2 = z_proj_w[tid * 3 + 2];
        float zb = z_proj_b[tid];

        float u0 = wred64(w0 * t);
        float u1 = wred64(w1 * t);
        float u2 = wred64(w2 * t);
        float s  = wred64(zb * t);
        float tn = wred64(t * t);
        if (tid == 0) {
            float* pb = ws + b * 8;
            pb[0] = u0; pb[1] = u1; pb[2] = u2; pb[3] = s; pb[4] = tn;
        }

        if (b == 0) {   // weight-only constants, computed once
            float o0 = out_w[0 * 64 + tid];
            float o1 = out_w[1 * 64 + tid];
            float o2 = out_w[2 * 64 + tid];
            float G00 = wred64(w0 * w0), G01 = wred64(w0 * w1), G02 = wred64(w0 * w2);
            float G11 = wred64(w1 * w1), G12 = wred64(w1 * w2), G22 = wred64(w2 * w2);
            float M00 = wred64(o0 * w0), M01 = wred64(o0 * w1), M02 = wred64(o0 * w2);
            float M10 = wred64(o1 * w0), M11 = wred64(o1 * w1), M12 = wred64(o1 * w2);
            float M20 = wred64(o2 * w0), M21 = wred64(o2 * w1), M22 = wred64(o2 * w2);
            float v0  = wred64(o0 * zb), v1  = wred64(o1 * zb), v2  = wred64(o2 * zb);
            float g0  = wred64(w0 * zb), g1  = wred64(w1 * zb), g2  = wred64(w2 * zb);
            float bn  = wred64(zb * zb);
            if (tid == 0) {
                float* c = ws + 128;
                c[0] = G00; c[1] = G01; c[2] = G02; c[3] = G11; c[4] = G12; c[5] = G22;
                c[6] = M00; c[7] = M01; c[8] = M02;
                c[9] = M10; c[10] = M11; c[11] = M12;
                c[12] = M20; c[13] = M21; c[14] = M22;
                c[15] = v0; c[16] = v1; c[17] = v2;
                c[18] = g0; c[19] = g1; c[20] = g2;
                c[21] = bn;
            }
        }
    }
}

__global__ __launch_bounds__(256) void fuse_kernel(
    const float* __restrict__ z,        // (16,3,256,256)
    const float* __restrict__ out_bias, // (3)
    const float* __restrict__ log_gamma,
    const float* __restrict__ alpha_p,
    const float* __restrict__ c_p,
    const float* __restrict__ wv,       // (3)
    const float* __restrict__ ws,
    float* __restrict__ out)            // (16,3,256,256)
{
    const int blk = blockIdx.x;
    const int b   = blk >> 6;                                   // 64 blocks per batch
    const int p   = ((blk & 63) << 10) + (threadIdx.x << 2);    // pixel offset (4/thread)

    const float* C = ws + 128;
    const float G00 = C[0], G01 = C[1], G02 = C[2], G11 = C[3], G12 = C[4], G22 = C[5];
    const float M00 = C[6], M01 = C[7], M02 = C[8];
    const float M10 = C[9], M11 = C[10], M12 = C[11];
    const float M20 = C[12], M21 = C[13], M22 = C[14];
    const float v0 = C[15], v1 = C[16], v2 = C[17];
    const float g0 = C[18], g1 = C[19], g2 = C[20], bn = C[21];

    const float* pb = ws + b * 8;
    const float u0 = pb[0], u1 = pb[1], u2 = pb[2], s = pb[3], tn = pb[4];

    const float gamma = __expf(log_gamma[0]);
    const float alpha = alpha_p[0], cc = c_p[0];
    const float w0 = wv[0], w1 = wv[1], w2 = wv[2];
    const float invw = 1.0f / (w0 + w1 + w2 + 1e-8f);
    const float ob0 = out_bias[0], ob1 = out_bias[1], ob2 = out_bias[2];

    const float e0 = g0 - u0, e1 = g1 - u1, e2 = g2 - u2;
    const float d0 = bn - 2.f * s + tn;

    const float* zb = z + (size_t)b * 3 * HW_PIX + p;
    float4 q0 = *(const float4*)(zb);
    float4 q1 = *(const float4*)(zb + HW_PIX);
    float4 q2 = *(const float4*)(zb + 2 * HW_PIX);

    float X[4] = {q0.x, q0.y, q0.z, q0.w};
    float Y[4] = {q1.x, q1.y, q1.z, q1.w};
    float Z[4] = {q2.x, q2.y, q2.z, q2.w};
    float O0[4], O1[4], O2[4];

#pragma unroll
    for (int j = 0; j < 4; ++j) {
        const float x = X[j], y = Y[j], zc = Z[j];
        // k_lin = q.u + s
        const float klin = fmaf(x, u0, fmaf(y, u1, fmaf(zc, u2, s)));
        // quad = q^T G q
        const float quad = x * fmaf(2.f, fmaf(G01, y, G02 * zc), G00 * x)
                         + y * fmaf(2.f, G12 * zc, G11 * y)
                         + G22 * zc * zc;
        const float dist = quad + 2.f * fmaf(e0, x, fmaf(e1, y, e2 * zc)) + d0;
        const float krbf = __expf(-gamma * dist);
        float kp = fmaf(alpha, klin, cc);
        kp = kp * kp;
        const float k = (w0 * krbf + w1 * klin + w2 * kp) * invw;
        const float sig = 1.f / (1.f + __expf(-k));
        const float scale = 1.f + sig;

        const float m0 = fmaf(M00, x, fmaf(M01, y, fmaf(M02, zc, v0)));
        const float m1 = fmaf(M10, x, fmaf(M11, y, fmaf(M12, zc, v1)));
        const float m2 = fmaf(M20, x, fmaf(M21, y, fmaf(M22, zc, v2)));
        O0[j] = fmaf(scale, m0, ob0);
        O1[j] = fmaf(scale, m1, ob1);
        O2[j] = fmaf(scale, m2, ob2);
    }

    float* ob = out + (size_t)b * 3 * HW_PIX + p;
    *(float4*)(ob)              = make_float4(O0[0], O0[1], O0[2], O0[3]);
    *(float4*)(ob + HW_PIX)     = make_float4(O1[0], O1[1], O1[2], O1[3]);
    *(float4*)(ob + 2 * HW_PIX) = make_float4(O2[0], O2[1], O2[2], O2[3]);
}

extern "C" void kernel_launch(void* const* d_in, const int* in_sizes, int n_in,
                              void* d_out, int out_size, void* d_ws, size_t ws_size,
                              hipStream_t stream) {
    const float* z           = (const float*)d_in[0];
    const float* text_vec    = (const float*)d_in[1];
    const float* z_proj_w    = (const float*)d_in[2];
    const float* z_proj_b    = (const float*)d_in[3];
    const float* text_proj_w = (const float*)d_in[4];
    const float* text_proj_b = (const float*)d_in[5];
    const float* out_w       = (const float*)d_in[6];
    const float* out_b       = (const float*)d_in[7];
    const float* log_gamma   = (const float*)d_in[8];
    const float* alpha       = (const float*)d_in[9];
    const float* c           = (const float*)d_in[10];
    const float* w           = (const float*)d_in[11];
    float* out = (float*)d_out;
    float* ws  = (float*)d_ws;

    prep_kernel<<<NBATCH, 256, 0, stream>>>(text_vec, text_proj_w, text_proj_b,
                                            z_proj_w, z_proj_b, out_w, ws);
    fuse_kernel<<<NBATCH * 64, 256, 0, stream>>>(z, out_b, log_gamma, alpha, c, w,
                                                 ws, out);
}